// Round 1
// baseline (107.009 us; speedup 1.0000x reference)
//
#include <hip/hip_runtime.h>
#include <math.h>

#define NQ 9
#define BATCH 16
#define H 28
#define W 28
#define NOUT 26                      // (28-3)/1 + 1
#define P_TOTAL (BATCH * NOUT * NOUT) // 10816 patches

struct Cf { float re, im; };

__device__ __forceinline__ Cf cmul(Cf a, Cf b) {
    return { a.re * b.re - a.im * b.im, a.re * b.im + a.im * b.re };
}
__device__ __forceinline__ Cf cadd(Cf a, Cf b) { return { a.re + b.re, a.im + b.im }; }

// One wave (64 lanes) per patch. State: 512 complex amps = 8 per lane.
// index i (9 bits): lane = bits 8..3, r = bits 2..0. Qubit q <-> bit (8-q).
__global__ __launch_bounds__(256) void qconv_kernel(const float* __restrict__ x,
                                                    const float* __restrict__ theta,
                                                    float* __restrict__ out) {
    int gtid = blockIdx.x * blockDim.x + threadIdx.x;
    int wave = gtid >> 6;
    int lane = gtid & 63;
    if (wave >= P_TOTAL) return;

    int b   = wave / (NOUT * NOUT);
    int rem = wave % (NOUT * NOUT);
    int i0  = rem / NOUT;
    int j0  = rem % NOUT;

    // ---- features -> cos/sin of f/2 (RX data gates) ----
    float cf[NQ], sf[NQ];
    const float* img = x + b * H * W;
    #pragma unroll
    for (int q = 0; q < NQ; ++q) {
        int r = i0 + q / 3, c = j0 + q % 3;
        float half = 0.5f * img[r * W + c];
        cf[q] = cosf(half);
        sf[q] = sinf(half);
    }

    // ---- init product state with CZ-ring sign folded in ----
    // amp(i) = sign_cz(i) * (-i)^popcount(i) * prod_q (b_q ? sin : cos)
    Cf st[8];
    #pragma unroll
    for (int r = 0; r < 8; ++r) {
        int idx = (lane << 3) | r;
        float mag = 1.0f;
        int pc = 0, cz = 0;
        int bits[NQ];
        #pragma unroll
        for (int q = 0; q < NQ; ++q) {
            int bq = (idx >> (8 - q)) & 1;
            bits[q] = bq;
            mag *= bq ? sf[q] : cf[q];
            pc += bq;
        }
        #pragma unroll
        for (int q = 0; q < NQ - 1; ++q) cz += bits[q] & bits[q + 1];
        cz += bits[0] & bits[NQ - 1];
        if (cz & 1) mag = -mag;
        Cf a;
        switch (pc & 3) {             // (-i)^pc
            case 0:  a = {  mag, 0.0f }; break;
            case 1:  a = { 0.0f, -mag }; break;
            case 2:  a = { -mag, 0.0f }; break;
            default: a = { 0.0f,  mag }; break;
        }
        st[r] = a;
    }

    // ---- 9 combined rotation gates G = RZ(pi*t2) * RY(pi*t1) * RX(pi*t0) ----
    const float PI = 3.14159265358979323846f;
    #pragma unroll
    for (int q = 0; q < NQ; ++q) {
        float a  = 0.5f * PI * theta[q * 3 + 0];
        float bb = 0.5f * PI * theta[q * 3 + 1];
        float cc = 0.5f * PI * theta[q * 3 + 2];
        float ca = cosf(a),  sa = sinf(a);
        float cb = cosf(bb), sb = sinf(bb);
        float cz = cosf(cc), sz = sinf(cc);
        // RY*RX
        Cf t00 = {  cb * ca,  sb * sa };
        Cf t01 = { -sb * ca, -cb * sa };
        Cf t10 = {  sb * ca, -cb * sa };
        Cf t11 = {  cb * ca, -sb * sa };
        Cf em = { cz, -sz };   // e^{-i c/2}
        Cf ep = { cz,  sz };   // e^{+i c/2}
        Cf g00 = cmul(em, t00), g01 = cmul(em, t01);
        Cf g10 = cmul(ep, t10), g11 = cmul(ep, t11);

        if (q >= 6) {
            // in-register pairs, stride m = 1 << (8-q)
            const int m = 1 << (8 - q);
            #pragma unroll
            for (int r = 0; r < 8; ++r) {
                if (!(r & m)) {
                    Cf a0 = st[r], a1 = st[r | m];
                    st[r]     = cadd(cmul(g00, a0), cmul(g01, a1));
                    st[r | m] = cadd(cmul(g10, a0), cmul(g11, a1));
                }
            }
        } else {
            // cross-lane pairs via shfl_xor, lane bit (5-q)
            const int xm  = 1 << (5 - q);
            const int bit = (lane >> (5 - q)) & 1;
            #pragma unroll
            for (int r = 0; r < 8; ++r) {
                Cf mine = st[r];
                Cf other;
                other.re = __shfl_xor(mine.re, xm, 64);
                other.im = __shfl_xor(mine.im, xm, 64);
                if (bit == 0)
                    st[r] = cadd(cmul(g00, mine), cmul(g01, other));
                else
                    st[r] = cadd(cmul(g10, other), cmul(g11, mine));
            }
        }
    }

    // ---- measure qubit 0 (lane bit 5 == 1 -> lanes 32..63) ----
    float p = 0.0f;
    if (lane & 32) {
        #pragma unroll
        for (int r = 0; r < 8; ++r)
            p += st[r].re * st[r].re + st[r].im * st[r].im;
    }
    #pragma unroll
    for (int off = 32; off >= 1; off >>= 1)
        p += __shfl_xor(p, off, 64);

    if (lane == 0) out[wave] = p;
}

extern "C" void kernel_launch(void* const* d_in, const int* in_sizes, int n_in,
                              void* d_out, int out_size, void* d_ws, size_t ws_size,
                              hipStream_t stream) {
    const float* x     = (const float*)d_in[0];
    const float* theta = (const float*)d_in[1];
    float* out         = (float*)d_out;
    // P_TOTAL waves, 4 waves (256 threads) per block -> 2704 blocks exactly
    const int threads = 256;
    const int blocks  = (P_TOTAL * 64 + threads - 1) / threads;
    qconv_kernel<<<blocks, threads, 0, stream>>>(x, theta, out);
}

// Round 2
// 55.253 us; speedup vs baseline: 1.9367x; 1.9367x over previous
//
#include <hip/hip_runtime.h>
#include <math.h>

#define NQ 9
#define BATCH 16
#define H 28
#define W 28
#define NOUT 26                       // (28-3)/1 + 1
#define P_TOTAL (BATCH * NOUT * NOUT) // 10816 outputs

// Closed form derived from the circuit structure:
//   state = (CZ-ring diagonal) applied to a product state, then a tensor
//   product of single-qubit gates, then measure P(q0=1).
//   U† (P1 ⊗ I) U = (U0† P1 U0) ⊗ I  -> only qubit-0's RX/RY angles survive
//   (RZ is diagonal, commutes with P1). Cross term picks up the CZ-ring
//   neighbors of qubit 0 (qubits 1 and 8) as cos(f1)*cos(f8).
//
//   P = 0.5 * (1 - cos(a)cos(b)cos(f0) + sin(a)cos(b)sin(f0)cos(f1)cos(f8))
//   a = pi*theta[0], b = pi*theta[1]
//   f0 = x[b][i][j], f1 = x[b][i][j+1], f8 = x[b][i+2][j+2]
__global__ __launch_bounds__(256) void qconv_closed_form(const float* __restrict__ x,
                                                         const float* __restrict__ theta,
                                                         float* __restrict__ out) {
    int t = blockIdx.x * blockDim.x + threadIdx.x;
    if (t >= P_TOTAL) return;

    int b   = t / (NOUT * NOUT);
    int rem = t % (NOUT * NOUT);
    int i0  = rem / NOUT;
    int j0  = rem % NOUT;

    const float PI = 3.14159265358979323846f;
    float a  = PI * theta[0];
    float bb = PI * theta[1];
    float ca = cosf(a), sa = sinf(a);
    float cb = cosf(bb);

    const float* img = x + b * H * W;
    float f0 = img[i0 * W + j0];
    float f1 = img[i0 * W + j0 + 1];
    float f8 = img[(i0 + 2) * W + j0 + 2];

    float p = 0.5f * (1.0f
                      - ca * cb * cosf(f0)
                      + sa * cb * sinf(f0) * cosf(f1) * cosf(f8));
    out[t] = p;
}

extern "C" void kernel_launch(void* const* d_in, const int* in_sizes, int n_in,
                              void* d_out, int out_size, void* d_ws, size_t ws_size,
                              hipStream_t stream) {
    const float* x     = (const float*)d_in[0];
    const float* theta = (const float*)d_in[1];
    float* out         = (float*)d_out;
    const int threads = 256;
    const int blocks  = (P_TOTAL + threads - 1) / threads;  // 43
    qconv_closed_form<<<blocks, threads, 0, stream>>>(x, theta, out);
}